// Round 1
// baseline (55.800 us; speedup 1.0000x reference)
//
#include <hip/hip_runtime.h>

// loss = (2n*S2 - 2*S1^2) / (n*(n-1)),  S1 = sum(e), S2 = sum(e^2), e = pred - tgt
// n = 16384 -> 128 KB total input. Single launch, single block (avoids a second
// dispatch / atomics). 1024 threads = 16 waves on one CU; float4 loads, 4 vecs
// per thread per array, shuffle + LDS reduction.

#define RDL_BLOCK 1024

__global__ __launch_bounds__(RDL_BLOCK)
void RelativeDifferenceLoss_kernel(const float* __restrict__ pred,
                                   const float* __restrict__ tgt,
                                   float* __restrict__ out, int n) {
    const float4* __restrict__ p4 = reinterpret_cast<const float4*>(pred);
    const float4* __restrict__ t4 = reinterpret_cast<const float4*>(tgt);
    const int tid = threadIdx.x;
    const int nvec = n >> 2;  // 4096 float4s per array

    float s1 = 0.f, s2 = 0.f;
    // 4 iterations for n=16384: 8 outstanding float4 loads/thread total -> good MLP
    for (int i = tid; i < nvec; i += RDL_BLOCK) {
        float4 p = p4[i];
        float4 t = t4[i];
        float e0 = p.x - t.x;
        float e1 = p.y - t.y;
        float e2 = p.z - t.z;
        float e3 = p.w - t.w;
        s1 += (e0 + e1) + (e2 + e3);
        s2 += (e0 * e0 + e1 * e1) + (e2 * e2 + e3 * e3);
    }

    // wave-level butterfly reduction across 64 lanes
    #pragma unroll
    for (int off = 32; off > 0; off >>= 1) {
        s1 += __shfl_down(s1, off, 64);
        s2 += __shfl_down(s2, off, 64);
    }

    __shared__ float ls1[RDL_BLOCK / 64];
    __shared__ float ls2[RDL_BLOCK / 64];
    const int wave = tid >> 6;
    const int lane = tid & 63;
    if (lane == 0) { ls1[wave] = s1; ls2[wave] = s2; }
    __syncthreads();

    if (tid == 0) {
        double S1 = 0.0, S2 = 0.0;
        #pragma unroll
        for (int w = 0; w < RDL_BLOCK / 64; ++w) {
            S1 += (double)ls1[w];
            S2 += (double)ls2[w];
        }
        const double nf = (double)n;
        const double loss = (2.0 * nf * S2 - 2.0 * S1 * S1) / (nf * (nf - 1.0));
        out[0] = (float)loss;
    }
}

extern "C" void kernel_launch(void* const* d_in, const int* in_sizes, int n_in,
                              void* d_out, int out_size, void* d_ws, size_t ws_size,
                              hipStream_t stream) {
    const float* pred = (const float*)d_in[0];
    const float* tgt  = (const float*)d_in[1];
    float* out = (float*)d_out;
    const int n = in_sizes[0];  // 16384

    RelativeDifferenceLoss_kernel<<<1, RDL_BLOCK, 0, stream>>>(pred, tgt, out, n);
}

// Round 2
// 55.329 us; speedup vs baseline: 1.0085x; 1.0085x over previous
//
#include <hip/hip_runtime.h>

// loss = (2n*S2 - 2*S1^2) / (n*(n-1)),  S1 = sum(e), S2 = sum(e^2), e = pred - tgt
// n = 16384 fixed -> 128 KB total input. Single launch, single block of 1024
// threads (16 waves, 1 CU). Compile-time trip count so all 8 float4 loads per
// thread issue before any waitcnt -> ONE memory latency round-trip instead of 4.

#define RDL_BLOCK 1024
#define RDL_N     16384
#define RDL_NVEC  (RDL_N / 4)          // 4096 float4 per array
#define RDL_VPT   (RDL_NVEC / RDL_BLOCK) // 4 float4 per thread per array

__global__ __launch_bounds__(RDL_BLOCK)
void RelativeDifferenceLoss_kernel(const float* __restrict__ pred,
                                   const float* __restrict__ tgt,
                                   float* __restrict__ out, int n) {
    const float4* __restrict__ p4 = reinterpret_cast<const float4*>(pred);
    const float4* __restrict__ t4 = reinterpret_cast<const float4*>(tgt);
    const int tid = threadIdx.x;

    float s1 = 0.f, s2 = 0.f;

    if (n == RDL_N) {
        // fast path: fully unrolled, 8 independent global_load_dwordx4 issued
        // back-to-back before any accumulation waits
        float4 p[RDL_VPT], t[RDL_VPT];
        #pragma unroll
        for (int k = 0; k < RDL_VPT; ++k) p[k] = p4[tid + k * RDL_BLOCK];
        #pragma unroll
        for (int k = 0; k < RDL_VPT; ++k) t[k] = t4[tid + k * RDL_BLOCK];
        #pragma unroll
        for (int k = 0; k < RDL_VPT; ++k) {
            float e0 = p[k].x - t[k].x;
            float e1 = p[k].y - t[k].y;
            float e2 = p[k].z - t[k].z;
            float e3 = p[k].w - t[k].w;
            s1 += (e0 + e1) + (e2 + e3);
            s2 += (e0 * e0 + e1 * e1) + (e2 * e2 + e3 * e3);
        }
    } else {
        // generic fallback (wave-uniform branch; never taken for this problem)
        const int nvec = n >> 2;
        for (int i = tid; i < nvec; i += RDL_BLOCK) {
            float4 p = p4[i];
            float4 t = t4[i];
            float e0 = p.x - t.x;
            float e1 = p.y - t.y;
            float e2 = p.z - t.z;
            float e3 = p.w - t.w;
            s1 += (e0 + e1) + (e2 + e3);
            s2 += (e0 * e0 + e1 * e1) + (e2 * e2 + e3 * e3);
        }
    }

    // wave-level reduction across 64 lanes
    #pragma unroll
    for (int off = 32; off > 0; off >>= 1) {
        s1 += __shfl_down(s1, off, 64);
        s2 += __shfl_down(s2, off, 64);
    }

    __shared__ float ls1[RDL_BLOCK / 64];
    __shared__ float ls2[RDL_BLOCK / 64];
    const int wave = tid >> 6;
    const int lane = tid & 63;
    if (lane == 0) { ls1[wave] = s1; ls2[wave] = s2; }
    __syncthreads();

    if (tid == 0) {
        double S1 = 0.0, S2 = 0.0;
        #pragma unroll
        for (int w = 0; w < RDL_BLOCK / 64; ++w) {
            S1 += (double)ls1[w];
            S2 += (double)ls2[w];
        }
        const double nf = (double)n;
        const double loss = (2.0 * nf * S2 - 2.0 * S1 * S1) / (nf * (nf - 1.0));
        out[0] = (float)loss;
    }
}

extern "C" void kernel_launch(void* const* d_in, const int* in_sizes, int n_in,
                              void* d_out, int out_size, void* d_ws, size_t ws_size,
                              hipStream_t stream) {
    const float* pred = (const float*)d_in[0];
    const float* tgt  = (const float*)d_in[1];
    float* out = (float*)d_out;
    const int n = in_sizes[0];  // 16384

    RelativeDifferenceLoss_kernel<<<1, RDL_BLOCK, 0, stream>>>(pred, tgt, out, n);
}